// Round 14
// baseline (553.598 us; speedup 1.0000x reference)
//
#include <hip/hip_runtime.h>
#include <hip/hip_bf16.h>
#include <cstdint>

#define F_IN 256
#define F_H  16
#define F_P  8    // bf16 pairs per hidden row
#define F_C  40
#define GB   512  // gemm1 grid blocks
#define XS   32   // nodes per lsm block

// ---------------------------------------------------------------------------
// K1: t1[N,16] = x[N,256] @ W1[256,16] (bf16 pairs) + zero the 4 agg replicas.
// No x LDS staging: wave = 16 f-lanes x 4 quad-streams; per k4 step one LDS
// w-float4 (broadcast) + 4 global x-float4 (16-way broadcast, line-sequential).
// ---------------------------------------------------------------------------
__global__ __launch_bounds__(256) void gemm1_kernel(
    const float* __restrict__ x, const float* __restrict__ W1,
    unsigned* __restrict__ t1, uint4* __restrict__ aggz, int N) {
  __shared__ float wlds[F_H * 260];    // transposed [f][k], stride 260
  const int tid = threadIdx.x;

  // zero agg1a|agg1b|agg2a|agg2b (4 * N*8 u32 = N*8 uint4)
  {
    const size_t tot = (size_t)N * F_P;        // uint4 count
    for (size_t i = blockIdx.x * 256 + tid; i < tot; i += (size_t)GB * 256)
      aggz[i] = make_uint4(0u, 0u, 0u, 0u);
  }

  // stage W1 transposed: global [k][f] -> lds [f][k]
  for (int i = tid; i < F_IN * F_H; i += 256) {
    int k = i >> 4, f = i & 15;
    wlds[f * 260 + k] = W1[i];
  }
  __syncthreads();

  const int lane = tid & 63;
  const int wv   = tid >> 6;           // wave 0..3
  const int f    = lane & 15;
  const int qs   = lane >> 4;          // quad-stream 0..3
  const float4* wf4 = reinterpret_cast<const float4*>(&wlds[f * 260]);
  const float4* x4  = reinterpret_cast<const float4*>(x);

  for (int nb = blockIdx.x * 64 + wv * 16 + qs * 4; nb < N; nb += GB * 64) {
    int n0 = nb, n1 = nb + 1, n2 = nb + 2, n3 = nb + 3;
    // clamp for safe loads (stores guarded below)
    int c1 = n1 < N ? n1 : N - 1;
    int c2 = n2 < N ? n2 : N - 1;
    int c3 = n3 < N ? n3 : N - 1;
    const float4* xr0 = x4 + (size_t)n0 * 64;
    const float4* xr1 = x4 + (size_t)c1 * 64;
    const float4* xr2 = x4 + (size_t)c2 * 64;
    const float4* xr3 = x4 + (size_t)c3 * 64;
    float a0 = 0.f, a1 = 0.f, a2 = 0.f, a3 = 0.f;
#pragma unroll 8
    for (int k4 = 0; k4 < 64; ++k4) {
      float4 w = wf4[k4];
      float4 v0 = xr0[k4], v1 = xr1[k4], v2 = xr2[k4], v3 = xr3[k4];
      a0 = fmaf(v0.x, w.x, a0); a0 = fmaf(v0.y, w.y, a0);
      a0 = fmaf(v0.z, w.z, a0); a0 = fmaf(v0.w, w.w, a0);
      a1 = fmaf(v1.x, w.x, a1); a1 = fmaf(v1.y, w.y, a1);
      a1 = fmaf(v1.z, w.z, a1); a1 = fmaf(v1.w, w.w, a1);
      a2 = fmaf(v2.x, w.x, a2); a2 = fmaf(v2.y, w.y, a2);
      a2 = fmaf(v2.z, w.z, a2); a2 = fmaf(v2.w, w.w, a2);
      a3 = fmaf(v3.x, w.x, a3); a3 = fmaf(v3.y, w.y, a3);
      a3 = fmaf(v3.z, w.z, a3); a3 = fmaf(v3.w, w.w, a3);
    }
    // pack adjacent features: even f takes odd partner via shfl_xor(1)
    float p0 = __shfl_xor(a0, 1), p1 = __shfl_xor(a1, 1);
    float p2 = __shfl_xor(a2, 1), p3 = __shfl_xor(a3, 1);
    if ((f & 1) == 0) {
      int pp = f >> 1;
      __hip_bfloat162 h;
      h = __halves2bfloat162(__float2bfloat16(a0), __float2bfloat16(p0));
      t1[(size_t)n0 * F_P + pp] = *reinterpret_cast<unsigned*>(&h);
      if (n1 < N) {
        h = __halves2bfloat162(__float2bfloat16(a1), __float2bfloat16(p1));
        t1[(size_t)n1 * F_P + pp] = *reinterpret_cast<unsigned*>(&h);
      }
      if (n2 < N) {
        h = __halves2bfloat162(__float2bfloat16(a2), __float2bfloat16(p2));
        t1[(size_t)n2 * F_P + pp] = *reinterpret_cast<unsigned*>(&h);
      }
      if (n3 < N) {
        h = __halves2bfloat162(__float2bfloat16(a3), __float2bfloat16(p3));
        t1[(size_t)n3 * F_P + pp] = *reinterpret_cast<unsigned*>(&h);
      }
    }
  }
}

// ---------------------------------------------------------------------------
// K2: scatter layer1 — agg1{a,b}[dst] += t1[src]*w (parity-split replicas).
// ---------------------------------------------------------------------------
__global__ __launch_bounds__(256) void scatter1_kernel(
    const __hip_bfloat162* __restrict__ t1, const int* __restrict__ ei,
    const float* __restrict__ ew, __hip_bfloat162* __restrict__ agg1a,
    __hip_bfloat162* __restrict__ agg1b, int N, int E) {
  int gid = blockIdx.x * 256 + threadIdx.x;
  int e = gid >> 3;
  int p = gid & 7;
  if (e >= E) return;
  int s = ei[e];
  int d = ei[E + e];
  if ((unsigned)s >= (unsigned)N || (unsigned)d >= (unsigned)N) return;
  float w = ew[e];
  __hip_bfloat162 tv = t1[(size_t)s * F_P + p];
  __hip_bfloat162 v = __halves2bfloat162(
      __float2bfloat16(__bfloat162float(tv.x) * w),
      __float2bfloat16(__bfloat162float(tv.y) * w));
  __hip_bfloat162* tgt = (e & 1) ? agg1b : agg1a;
  unsafeAtomicAdd(&tgt[(size_t)d * F_P + p], v);
}

// ---------------------------------------------------------------------------
// K3: scatter layer2 in hidden space — agg2{a,b}[dst] += relu(Σagg1+b1)*w.
// ---------------------------------------------------------------------------
__global__ __launch_bounds__(256) void scatter2_kernel(
    const __hip_bfloat162* __restrict__ agg1a,
    const __hip_bfloat162* __restrict__ agg1b, const float* __restrict__ b1,
    const int* __restrict__ ei, const float* __restrict__ ew,
    __hip_bfloat162* __restrict__ agg2a, __hip_bfloat162* __restrict__ agg2b,
    int N, int E) {
  int gid = blockIdx.x * 256 + threadIdx.x;
  int e = gid >> 3;
  int p = gid & 7;
  if (e >= E) return;
  int s = ei[e];
  int d = ei[E + e];
  if ((unsigned)s >= (unsigned)N || (unsigned)d >= (unsigned)N) return;
  float w = ew[e];
  float2 bb = reinterpret_cast<const float2*>(b1)[p];
  __hip_bfloat162 va = agg1a[(size_t)s * F_P + p];
  __hip_bfloat162 vb = agg1b[(size_t)s * F_P + p];
  float lo = fmaxf(__bfloat162float(va.x) + __bfloat162float(vb.x) + bb.x, 0.f) * w;
  float hi = fmaxf(__bfloat162float(va.y) + __bfloat162float(vb.y) + bb.y, 0.f) * w;
  __hip_bfloat162 v = __halves2bfloat162(__float2bfloat16(lo), __float2bfloat16(hi));
  __hip_bfloat162* tgt = (e & 1) ? agg2b : agg2a;
  unsafeAtomicAdd(&tgt[(size_t)d * F_P + p], v);
}

// ---------------------------------------------------------------------------
// K4: fused epilogue — out[n] = log_softmax((agg2a+agg2b)[n] @ W2 + b2)
// 256 thr, 32 nodes/block; 8 lanes/row, 5 classes/lane, shfl_xor reduce.
// ---------------------------------------------------------------------------
__global__ __launch_bounds__(256) void gemm2_lsm_kernel(
    const __hip_bfloat162* __restrict__ agg2a,
    const __hip_bfloat162* __restrict__ agg2b, const float* __restrict__ W2,
    const float* __restrict__ b2, float* __restrict__ out, int N) {
  __shared__ float w2lds[F_H * F_C];   // [k][c]
  __shared__ float b2lds[F_C];
  __shared__ float alds[XS * F_H];
  const int tid = threadIdx.x;
  const int nodeBase = blockIdx.x * XS;

  for (int i = tid; i < F_H * F_C; i += 256) w2lds[i] = W2[i];
  if (tid < F_C) b2lds[tid] = b2[tid];
  {
    int node = nodeBase + (tid >> 3);
    float lo = 0.f, hi = 0.f;
    if (node < N) {
      size_t idx = (size_t)node * F_P + (tid & 7);
      __hip_bfloat162 va = agg2a[idx];
      __hip_bfloat162 vb = agg2b[idx];
      lo = __bfloat162float(va.x) + __bfloat162float(vb.x);
      hi = __bfloat162float(va.y) + __bfloat162float(vb.y);
    }
    alds[(tid >> 3) * F_H + 2 * (tid & 7)]     = lo;
    alds[(tid >> 3) * F_H + 2 * (tid & 7) + 1] = hi;
  }
  __syncthreads();

  const int r = tid >> 3;              // local row
  const int l = tid & 7;               // lane in 8-group
  const int node = nodeBase + r;
  const float* arow = &alds[r * F_H];

  float acc[5];
#pragma unroll
  for (int j = 0; j < 5; ++j) {
    int c = l * 5 + j;
    float a = b2lds[c];
#pragma unroll
    for (int k = 0; k < F_H; ++k) a = fmaf(arow[k], w2lds[k * F_C + c], a);
    acc[j] = a;
  }

  float m = acc[0];
#pragma unroll
  for (int j = 1; j < 5; ++j) m = fmaxf(m, acc[j]);
#pragma unroll
  for (int off = 1; off < 8; off <<= 1) m = fmaxf(m, __shfl_xor(m, off, 8));

  float s = 0.f;
#pragma unroll
  for (int j = 0; j < 5; ++j) s += __expf(acc[j] - m);
#pragma unroll
  for (int off = 1; off < 8; off <<= 1) s += __shfl_xor(s, off, 8);

  float ml = m + __logf(s);
  if (node < N) {
#pragma unroll
    for (int j = 0; j < 5; ++j)
      out[(size_t)node * F_C + l * 5 + j] = acc[j] - ml;
  }
}

// ---------------------------------------------------------------------------
extern "C" void kernel_launch(void* const* d_in, const int* in_sizes, int n_in,
                              void* d_out, int out_size, void* d_ws, size_t ws_size,
                              hipStream_t stream) {
  const float* x  = (const float*)d_in[0];
  const int*   ei = (const int*)d_in[1];
  const float* ew = (const float*)d_in[2];
  const float* W1 = (const float*)d_in[3];
  const float* b1 = (const float*)d_in[4];
  const float* W2 = (const float*)d_in[5];
  const float* b2 = (const float*)d_in[6];
  float* out = (float*)d_out;

  const int N = in_sizes[0] / F_IN;
  const int E = in_sizes[2];

  // ws (bf16 pairs, each N*8 u32): t1 | agg1a | agg1b | agg2a | agg2b
  __hip_bfloat162* t1    = (__hip_bfloat162*)d_ws;
  __hip_bfloat162* agg1a = t1 + (size_t)N * F_P;
  __hip_bfloat162* agg1b = agg1a + (size_t)N * F_P;
  __hip_bfloat162* agg2a = agg1b + (size_t)N * F_P;
  __hip_bfloat162* agg2b = agg2a + (size_t)N * F_P;

  gemm1_kernel<<<GB, 256, 0, stream>>>(x, W1, (unsigned*)t1, (uint4*)agg1a, N);
  scatter1_kernel<<<((size_t)E * F_P + 255) / 256, 256, 0, stream>>>(
      t1, ei, ew, agg1a, agg1b, N, E);
  scatter2_kernel<<<((size_t)E * F_P + 255) / 256, 256, 0, stream>>>(
      agg1a, agg1b, b1, ei, ew, agg2a, agg2b, N, E);
  gemm2_lsm_kernel<<<(N + XS - 1) / XS, 256, 0, stream>>>(
      agg2a, agg2b, W2, b2, out, N);
}